// Round 11
// baseline (184.366 us; speedup 1.0000x reference)
//
#include <hip/hip_runtime.h>

// MHA forward: B=4, S=2048, D=1024, H=16, DK=64.
// out = softmax((xWq+bq)(xWk+bk)^T / 8)(xWv+bv) @ Wo + bo
// All GEMMs in bf16 MFMA (fp32 accum).

typedef unsigned short u16;
typedef unsigned int u32;
typedef __attribute__((ext_vector_type(8))) short bfx8;     // 8 bf16 (4 VGPR) MFMA operand
typedef __attribute__((ext_vector_type(4))) float f32x4;    // 16x16 MFMA accumulator
typedef __attribute__((ext_vector_type(16))) float f32x16;  // 32x32 MFMA accumulator
typedef __attribute__((ext_vector_type(4))) float fx4;
typedef __attribute__((ext_vector_type(8))) u16 u16x8;
typedef __attribute__((ext_vector_type(4))) u16 u16x4;
typedef __attribute__((ext_vector_type(4))) u32 u32x4;

__device__ __forceinline__ u16 f2bf(float f) {
  union { float f; u32 u; } v; v.f = f;
  u32 u = v.u;
  u += 0x7fffu + ((u >> 16) & 1u);   // round-to-nearest-even
  return (u16)(u >> 16);
}

__device__ __forceinline__ u32 cvtpk(float a, float b) {
  u32 r;
  asm("v_cvt_pk_bf16_f32 %0, %1, %2" : "=v"(r) : "v"(a), "v"(b));
  return r;
}

// async global->LDS, 16B per lane
__device__ __forceinline__ void gl_lds16(const void* g, void* l) {
  __builtin_amdgcn_global_load_lds((const __attribute__((address_space(1))) void*)g,
                                   (__attribute__((address_space(3))) void*)l, 16, 0, 0);
}

// ---------------- fused pre-pass: fp32->bf16 cvt (q,k,v) + 4x weight transpose ----------------
__global__ void prep(const float* __restrict__ q, const float* __restrict__ k,
                     const float* __restrict__ v, u16* __restrict__ inBase,
                     const float* __restrict__ W0, const float* __restrict__ W1,
                     const float* __restrict__ W2, const float* __restrict__ W3,
                     u16* __restrict__ WtBase) {
  __shared__ float tile[64][65];
  const int bid = blockIdx.x;
  const int t = threadIdx.x;
  if (bid < 12288) {
    const int z = bid >> 12, xb = bid & 4095;
    const float* in = z == 0 ? q : (z == 1 ? k : v);
    u16* out = inBase + (size_t)z * (8192ull * 1024);
    const int i = (xb * 256 + t) * 8;
    fx4 a = *(const fx4*)(in + i);
    fx4 b = *(const fx4*)(in + i + 4);
    u16x8 o;
    o[0] = f2bf(a[0]); o[1] = f2bf(a[1]); o[2] = f2bf(a[2]); o[3] = f2bf(a[3]);
    o[4] = f2bf(b[0]); o[5] = f2bf(b[1]); o[6] = f2bf(b[2]); o[7] = f2bf(b[3]);
    *(u16x8*)(out + i) = o;
  } else {
    const int wb = bid - 12288;
    const int z = wb >> 8, rem = wb & 255;
    const float* W = z == 0 ? W0 : (z == 1 ? W1 : (z == 2 ? W2 : W3));
    u16* Wt = WtBase + (size_t)z * (1024ull * 1024);
    const int n0 = (rem & 15) << 6, k0 = (rem >> 4) << 6;
    {
      int r = t >> 2, c = (t & 3) << 4;
      const float* src = W + (size_t)(k0 + r) * 1024 + n0 + c;
#pragma unroll
      for (int u = 0; u < 4; ++u) {
        fx4 vv = *(const fx4*)(src + u * 4);
        tile[r][c + u * 4 + 0] = vv[0];
        tile[r][c + u * 4 + 1] = vv[1];
        tile[r][c + u * 4 + 2] = vv[2];
        tile[r][c + u * 4 + 3] = vv[3];
      }
    }
    __syncthreads();
    {
      int nn = t >> 2, j = t & 3;
      u16x8 o0, o1;
#pragma unroll
      for (int e = 0; e < 8; ++e) o0[e] = f2bf(tile[(j << 4) + e][nn]);
#pragma unroll
      for (int e = 0; e < 8; ++e) o1[e] = f2bf(tile[(j << 4) + 8 + e][nn]);
      u16* dst = Wt + (size_t)(n0 + nn) * 1024 + k0 + (j << 4);
      *(u16x8*)dst = o0;
      *(u16x8*)(dst + 8) = o1;
    }
  }
}

// ---------------- GEMM body: 128x128 tile, BK=64, 2-phase dbuf (proven) ----------------
template <int EPI>
__device__ __forceinline__ void gemm_body(const u16* __restrict__ A, const u16* __restrict__ Bt,
                                          const float* __restrict__ bias, void* __restrict__ out,
                                          float scale, char* smem, int m0, int n0) {
  const int t = threadIdx.x;
  const int w = t >> 6, l = t & 63;
  const int lg = l >> 4, lr = l & 15;
  const int wr = w >> 1, wc = w & 1;

  f32x4 acc[4][4] = {};

  const int trow = t >> 3;
  const int scb = ((t & 7) << 4) ^ ((trow & 7) << 4);
  const char* gA = (const char*)A + (size_t)(m0 + trow) * 2048;
  const char* gB = (const char*)Bt + (size_t)(n0 + trow) * 2048;

#define GSTAGE(kt, buf)                                                        \
  do {                                                                         \
    _Pragma("unroll")                                                          \
    for (int i = 0; i < 4; ++i) {                                              \
      gl_lds16(gA + (size_t)i * 32 * 2048 + ((kt) << 7) + scb,                 \
               (buf) + (((i << 8) + (w << 6)) << 4));                          \
      gl_lds16(gB + (size_t)i * 32 * 2048 + ((kt) << 7) + scb,                 \
               (buf) + 16384 + (((i << 8) + (w << 6)) << 4));                  \
    }                                                                          \
  } while (0)

  GSTAGE(0, smem);
  __syncthreads();

  for (int kt = 0; kt < 16; ++kt) {
    char* sA = smem + ((kt & 1) << 15);
    char* sB = sA + 16384;
    if (kt < 15) GSTAGE(kt + 1, smem + (((kt + 1) & 1) << 15));

#pragma unroll
    for (int kk = 0; kk < 2; ++kk) {
      const int off = ((kk << 6) + (lg << 4)) ^ ((lr & 7) << 4);
      bfx8 av[4], bv[4];
#pragma unroll
      for (int fi = 0; fi < 4; ++fi)
        av[fi] = *(const bfx8*)(sA + ((wr << 6) + (fi << 4) + lr) * 128 + off);
#pragma unroll
      for (int fj = 0; fj < 4; ++fj)
        bv[fj] = *(const bfx8*)(sB + ((wc << 6) + (fj << 4) + lr) * 128 + off);
#pragma unroll
      for (int fi = 0; fi < 4; ++fi)
#pragma unroll
        for (int fj = 0; fj < 4; ++fj)
          acc[fi][fj] = __builtin_amdgcn_mfma_f32_16x16x32_bf16(av[fi], bv[fj], acc[fi][fj], 0, 0, 0);
    }
    __syncthreads();
  }
#undef GSTAGE

#pragma unroll
  for (int fj = 0; fj < 4; ++fj) {
    const int n = n0 + (wc << 6) + (fj << 4) + lr;
    const float bvl = bias[n];
#pragma unroll
    for (int fi = 0; fi < 4; ++fi) {
      if constexpr (EPI == 2) {
        const int h = n >> 6, d = n & 63;
        const int mm = m0 + (wr << 6) + (fi << 4) + (lg << 2);
        const int b = mm >> 11, s = mm & 2047;
        u16x4 pk4;
#pragma unroll
        for (int r = 0; r < 4; ++r) pk4[r] = f2bf(acc[fi][fj][r] + bvl);
        *(u16x4*)((u16*)out + (size_t)(b * 16 + h) * 131072 + (size_t)d * 2048 + s) = pk4;
      } else {
#pragma unroll
        for (int r = 0; r < 4; ++r) {
          const int m = m0 + (wr << 6) + (fi << 4) + (lg << 2) + r;
          const float val = (acc[fi][fj][r] + bvl) * scale;
          if constexpr (EPI == 0) {
            const int b = m >> 11, s = m & 2047, h = n >> 6, d = n & 63;
            ((u16*)out)[(((size_t)(b * 16 + h) * 2048 + s) << 6) + d] = f2bf(val);
          } else {
            ((float*)out)[((size_t)m << 10) + n] = val;
          }
        }
      }
    }
  }
}

// XCD panel grouping (bijective)
__device__ __forceinline__ void xcd_remap(int& m0, int& n0) {
  const int lin = blockIdx.x + (blockIdx.y << 3);
  const int c = lin & 7, j = lin >> 3;
  m0 = (((j & 7) << 3) + c) << 7;
  n0 = (j >> 3) << 7;
}

__global__ void __launch_bounds__(256, 2)
gemm_qkv(const u16* __restrict__ A0, const u16* __restrict__ Wt0,
         const float* __restrict__ bq, const float* __restrict__ bk,
         const float* __restrict__ bv, u16* __restrict__ out0, u16* __restrict__ vt) {
  __shared__ __align__(16) char smem[65536];
  const int z = blockIdx.z;
  int m0, n0;
  xcd_remap(m0, n0);
  const u16* A = A0 + (size_t)z * (8192ull * 1024);
  const u16* Bt = Wt0 + (size_t)z * (1024ull * 1024);
  if (z == 2) {
    gemm_body<2>(A, Bt, bv, vt, 1.0f, smem, m0, n0);
  } else {
    const float* bias = z == 0 ? bq : bk;
    const float scale = z == 0 ? 0.18033688011112042f : 1.0f;  // 0.125*log2(e) into Q
    gemm_body<0>(A, Bt, bias, out0 + (size_t)z * (8192ull * 1024), scale, smem, m0, n0);
  }
}

__global__ void __launch_bounds__(256, 2)
gemm_o(const u16* __restrict__ A, const u16* __restrict__ Bt,
       const float* __restrict__ bias, float* __restrict__ out) {
  __shared__ __align__(16) char smem[65536];
  int m0, n0;
  xcd_remap(m0, n0);
  gemm_body<1>(A, Bt, bias, out, 1.0f, smem, m0, n0);
}

// ---------------- Flash attention: 32x32 MFMA, in-register P, octave-aware LDS swizzle ----
// Q (pre-scaled by 0.125*log2e), K: [pair][2048][64] bf16 ; Vt: [pair][64][2048] bf16.
// 512 thr = 8 waves x 32 q-rows. KV tile 64. S^T = mfma32(K, Q): lane owns q = l&31.
// P stays in registers via cvt_pk + permlane32_swap (T12). No-max softmax.
// LDS swizzle key now covers the row OCTAVE: key(row) = (row&7) ^ (((row>>3)&3)<<1).
// With 128B rows every row starts at bank 0, so the 8 lanes of a (l&7)-group
// {l31 = c+8o} x {hi} previously hit only 2 slots (4-way conflict on every
// ds_read_b128, 8.39M conflict cycles). New key -> slot = 2ks^hi^c^(o<<1):
// all 8 distinct -> 256 bank-accesses spread perfectly over 32 banks.
// Write side carries the matching inverse on the global source (rule #21).
__global__ void __launch_bounds__(512, 4)
attn_fwd(const u16* __restrict__ Qg, const u16* __restrict__ Kg,
         const u16* __restrict__ Vtg, u16* __restrict__ Og) {
  __shared__ __align__(16) char smem[65536];
  const int t = threadIdx.x;
  const int w = t >> 6, l = t & 63;
  const int l31 = l & 31, hi = l >> 5;

  const int id = blockIdx.x;               // 512 blocks
  const int xcd = id & 7, slot = id >> 3;  // slot 0..63
  const int pair = ((slot >> 3) << 3) + xcd;
  const int q0 = (slot & 7) << 8;

  const char* Qb = (const char*)Qg + ((size_t)pair << 18);
  const char* Kb = (const char*)Kg + ((size_t)pair << 18);
  const char* Vb = (const char*)Vtg + ((size_t)pair << 18);

  const int trow = t >> 3;
  // inverse-swizzled global source col: key(trow) = (trow&7) ^ (((trow>>3)&3)<<1)
  const int scb = (((t & 7) ^ (trow & 7) ^ (((trow >> 3) & 3) << 1)) << 4);
  const int ldst = (w << 10);
  // read swizzle key for row = mb*32 + l31 (octave = l31>>3): key = (l&7) ^ ((l31>>3)<<1)
  const int swz = (((l & 7) ^ ((l31 >> 3) << 1)) << 4);

  // Q fragments (B-operand): lane holds Q[q = l&31][d = ks*16 + hi*8 + j]
  bfx8 qf[4];
#pragma unroll
  for (int ks = 0; ks < 4; ++ks)
    qf[ks] = *(const bfx8*)(Qb + (size_t)(q0 + (w << 5) + l31) * 128 + (ks << 5) + (hi << 4));

  f32x16 accO[2] = {};
  float Lp = 0.f;

#define ASTAGE(kt, buf)                                                         \
  do {                                                                          \
    gl_lds16(Kb + (size_t)(kt) * 8192 + (size_t)trow * 128 + scb, (buf) + ldst);\
    gl_lds16(Vb + (size_t)trow * 4096 + (size_t)(kt) * 128 + scb,               \
             (buf) + 8192 + ldst);                                              \
  } while (0)

  ASTAGE(0, smem);
  ASTAGE(1, smem + 16384);
  __syncthreads();

  for (int it2 = 0; it2 < 16; ++it2) {
    const int tt = it2 << 1;
    // stage tiles tt+2, tt+3 into the two buffers freed by the previous super-iter
    if (tt + 2 < 32) ASTAGE(tt + 2, smem + (((tt + 2) & 3) << 14));
    if (tt + 3 < 32) ASTAGE(tt + 3, smem + (((tt + 3) & 3) << 14));

#pragma unroll
    for (int u = 0; u < 2; ++u) {
      char* bK = smem + (((tt + u) & 3) << 14);
      char* bV = bK + 8192;

      // ---- S^T = K · Q^T : accS[mb] covers kv = mb*32 + [(r&3)+8(r>>2)+4hi], q = l&31 ----
      f32x16 accS[2] = {{}, {}};
      __builtin_amdgcn_s_setprio(1);
#pragma unroll
      for (int mb = 0; mb < 2; ++mb) {
        bfx8 kf[4];
#pragma unroll
        for (int ks = 0; ks < 4; ++ks)
          kf[ks] = *(const bfx8*)(bK + (((mb << 5) + l31) << 7) + (((ks << 5) + (hi << 4)) ^ swz));
#pragma unroll
        for (int ks = 0; ks < 4; ++ks)
          accS[mb] = __builtin_amdgcn_mfma_f32_32x32x16_bf16(kf[ks], qf[ks], accS[mb], 0, 0, 0);
      }
      __builtin_amdgcn_s_setprio(0);

      // ---- softmax-lite + in-register P->A-frag (cvt_pk pairs + permlane32_swap) ----
      bfx8 pa[4];
#pragma unroll
      for (int mb = 0; mb < 2; ++mb) {
#pragma unroll
        for (int r = 0; r < 16; ++r) {
          accS[mb][r] = __builtin_amdgcn_exp2f(accS[mb][r]);
          Lp += accS[mb][r];
        }
#pragma unroll
        for (int half = 0; half < 2; ++half) {
          u32 a0 = cvtpk(accS[mb][8 * half + 0], accS[mb][8 * half + 1]);
          u32 a1 = cvtpk(accS[mb][8 * half + 2], accS[mb][8 * half + 3]);
          u32 b0 = cvtpk(accS[mb][8 * half + 4], accS[mb][8 * half + 5]);
          u32 b1 = cvtpk(accS[mb][8 * half + 6], accS[mb][8 * half + 7]);
          asm volatile("v_permlane32_swap_b32 %0, %1" : "+v"(a0), "+v"(b0));
          asm volatile("v_permlane32_swap_b32 %0, %1" : "+v"(a1), "+v"(b1));
          u32x4 pk; pk[0] = a0; pk[1] = a1; pk[2] = b0; pk[3] = b1;
          pa[(mb << 1) + half] = *(bfx8*)&pk;  // P[q=l&31][kv = 16*(2mb+half) + hi*8 + j]
        }
      }

      // ---- O += P · V : vf lane holds V[kv = ks*16+hi*8+j][d = nb*32 + l&31] ----
      __builtin_amdgcn_s_setprio(1);
#pragma unroll
      for (int ks = 0; ks < 4; ++ks) {
        bfx8 vf0 = *(const bfx8*)(bV + ((0 + l31) << 7) + (((ks << 5) + (hi << 4)) ^ swz));
        bfx8 vf1 = *(const bfx8*)(bV + ((32 + l31) << 7) + (((ks << 5) + (hi << 4)) ^ swz));
        accO[0] = __builtin_amdgcn_mfma_f32_32x32x16_bf16(pa[ks], vf0, accO[0], 0, 0, 0);
        accO[1] = __builtin_amdgcn_mfma_f32_32x32x16_bf16(pa[ks], vf1, accO[1], 0, 0, 0);
      }
      __builtin_amdgcn_s_setprio(0);
    }

    __syncthreads();  // drains stages tt+2/tt+3; all waves done reading bufs tt, tt+1
  }
#undef ASTAGE

  // ---- epilogue: L total (lane + hi-partner), bpermute broadcast, direct stores ----
  const float Ltot = Lp + __shfl_xor(Lp, 32);   // lane l holds L[q0w + (l&31)]
  const int b = pair >> 4, h = pair & 15;
  u16* dstBase = Og + (((size_t)(b * 2048 + q0 + (w << 5))) << 10) + (h << 6) + l31;
#pragma unroll
  for (int r = 0; r < 16; ++r) {
    const int ql = (r & 3) + ((r >> 2) << 3) + (hi << 2);  // output q-row of reg r
    const float Lr = __shfl(Ltot, ql);                     // bpermute broadcast
    const float rinv = __builtin_amdgcn_rcpf(Lr);
    u16* dst = dstBase + ((size_t)ql << 10);
    dst[0]  = f2bf(accO[0][r] * rinv);
    dst[32] = f2bf(accO[1][r] * rinv);
  }
}

extern "C" void kernel_launch(void* const* d_in, const int* in_sizes, int n_in,
                              void* d_out, int out_size, void* d_ws, size_t ws_size,
                              hipStream_t stream) {
  const float* q  = (const float*)d_in[0];
  const float* k  = (const float*)d_in[1];
  const float* v  = (const float*)d_in[2];
  const float* Wq = (const float*)d_in[3];
  const float* bq = (const float*)d_in[4];
  const float* Wk = (const float*)d_in[5];
  const float* bk = (const float*)d_in[6];
  const float* Wv = (const float*)d_in[7];
  const float* bv = (const float*)d_in[8];
  const float* Wo = (const float*)d_in[9];
  const float* bo = (const float*)d_in[10];
  float* out = (float*)d_out;
  char* ws = (char*)d_ws;

  const size_t MB = 1024 * 1024;
  if (ws_size < 104 * MB) return;

  u16* inq = (u16*)(ws + 0 * MB);    // [3x contiguous 16MB] cvt'd q,k,v; later Ob overlay
  u16* wqt = (u16*)(ws + 48 * MB);   // [4x contiguous 2MB: Wq^T, Wk^T, Wv^T, Wo^T]
  u16* wot = (u16*)(ws + 54 * MB);
  u16* Qh  = (u16*)(ws + 56 * MB);   // Qh @56, Kh @72
  u16* Kh  = (u16*)(ws + 72 * MB);
  u16* Vth = (u16*)(ws + 88 * MB);   // Vt[pair][64][2048] written directly by z==2
  u16* Ob  = inq;                    // overlays inq (dead after QKV GEMM)

  prep<<<13312, 256, 0, stream>>>(q, k, v, inq, Wq, Wk, Wv, Wo, wqt);
  gemm_qkv<<<dim3(8, 64, 3), 256, 0, stream>>>(inq, wqt, bq, bk, bv, Qh, Vth);
  attn_fwd<<<512, 512, 0, stream>>>(Qh, Kh, Vth, Ob);
  gemm_o<<<dim3(8, 64), 256, 0, stream>>>(Ob, wot, bo, out);
}